// Round 12
// baseline (74.960 us; speedup 1.0000x reference)
//
#include <hip/hip_runtime.h>
#include <hip/hip_bf16.h>
#include <stdint.h>
#include <stddef.h>

// ---------------------------------------------------------------------------
// FixedEmbedderNN — round 12:
//  (1) single merged prep kernel (associativity: x@WLf = (x@W1)@W2 removes the
//      pre1->pre2 dependency; 3 launches -> 2).
//  (2) mainK staging via __builtin_amdgcn_global_load_lds width=16 (linear
//      dest = wave-uniform base + lane*16) — removes ~1/3 of DS-pipe work.
//  mainK phases/mappings identical to r11 (verified): table halves
//  [2][20][50][64] slot-major; gather lane=(r8,s) bank-perfect b128; hstate
//  128x136 u16; tail = numeric MFMA (a1p 8-run col map) + hstate add + LN0 +
//  GEMM2' + LN1 + GEMM3'.
// ---------------------------------------------------------------------------

typedef __attribute__((ext_vector_type(8))) short short8;
typedef __attribute__((ext_vector_type(4))) float f32x4;
typedef __attribute__((ext_vector_type(2))) uint32_t uint32x2;

#define LN_EPS 1e-5f

#define GLDS16(g, l) __builtin_amdgcn_global_load_lds( \
    (const __attribute__((address_space(1))) uint32_t*)(g), \
    (__attribute__((address_space(3))) uint32_t*)(l), 16, 0, 0)

__device__ __forceinline__ float bflo(uint32_t u){ union{uint32_t u;float f;} c; c.u = u<<16; return c.f; }
__device__ __forceinline__ float bfhi(uint32_t u){ union{uint32_t u;float f;} c; c.u = u&0xffff0000u; return c.f; }
__device__ __forceinline__ uint16_t f2bf(float f){
  union{ __hip_bfloat16 h; uint16_t u; } c; c.h = __float2bfloat16(f); return c.u;
}
__device__ __forceinline__ uint32_t pkbf(float lo, float hi){
  return (uint32_t)f2bf(lo) | ((uint32_t)f2bf(hi)<<16);
}

// ---------------- merged prep kernel (no inter-kernel deps) ----------------
// blocks: [0,1000) tcat | [1000,1032) wl2p | 1032 bf1p | 1033 boutp |
//         [1034,1066) woutp | [1066,1098) a1p (t=idx>>2, q=idx&3)
__global__ __launch_bounds__(128) void prep(
    const float* __restrict__ emb,
    const float* __restrict__ W_num, const float* __restrict__ b_num,
    const float* __restrict__ W_in,  const float* __restrict__ b_in,
    const float* __restrict__ W1,    const float* __restrict__ b1,
    const float* __restrict__ W2,    const float* __restrict__ b2,
    const float* __restrict__ ln_g,  const float* __restrict__ ln_b,
    const float* __restrict__ W_out, const float* __restrict__ b_out,
    uint16_t* __restrict__ tcatp,   // [2][20][50][64] bf16 slot-major
    uint16_t* __restrict__ wl2p,    // WL1' transposed pack
    float* __restrict__ bf1p,       // bf1' permuted
    uint16_t* __restrict__ a1p,     // A1^T pack, 8-run col map
    uint16_t* __restrict__ woutp,   // Wout' transposed pack
    float* __restrict__ boutp)      // bout' permuted
{
  const int b = blockIdx.x, j = threadIdx.x;
  __shared__ float sh[3072];

  if (b < 1000) {
    // tcat[f][c] = ((emb[f][c] @ W_in_f) @ W1_0) @ W2_0, slot-major store
    const int f = b / 50, c = b % 50;
    float* s1 = sh;           // 128
    float* u  = sh + 128;     // 256
    {
      const float* e  = emb + (f*50 + c)*32;
      const float* wi = W_in + (size_t)f*32*128 + j;
      float s = 0.f;
      for (int e2 = 0; e2 < 32; e2++) s = fmaf(e[e2], wi[e2*128], s);
      s1[j] = s;
    }
    __syncthreads();
    #pragma unroll
    for (int half = 0; half < 2; half++) {
      const int m = j + half*128;
      const float* w1c = W1 + m;                  // W1_0[k][m]
      float sa = 0.f, sb = 0.f;
      for (int k = 0; k < 128; k += 2) {
        sa = fmaf(s1[k],   w1c[k*256],       sa);
        sb = fmaf(s1[k+1], w1c[(k+1)*256],   sb);
      }
      u[m] = sa + sb;
    }
    __syncthreads();
    {
      const float* w2c = W2 + j;                  // W2_0[m][j]
      float sa = 0.f, sb = 0.f, sc = 0.f, sd = 0.f;
      for (int m = 0; m < 256; m += 4) {
        sa = fmaf(u[m],   w2c[m*128],       sa);
        sb = fmaf(u[m+1], w2c[(m+1)*128],   sb);
        sc = fmaf(u[m+2], w2c[(m+2)*128],   sc);
        sd = fmaf(u[m+3], w2c[(m+3)*128],   sd);
      }
      const float s2v = (sa + sb) + (sc + sd);
      const int t = j >> 4, g = (j >> 2) & 3, r = j & 3;
      const int h = t >> 2, jj = t & 3;
      const int slot = 2*g + (jj >> 1);
      tcatp[((h*20 + f)*50 + c)*64 + slot*8 + (jj & 1)*4 + r] = f2bf(s2v);
    }
  } else if (b < 1032) {
    // wl2p: entry = g0[k] * WL1[k][col], WL1[k][col] = W1_1[k] . W2_1[:,col]
    const int p = b - 1000, t = p >> 2, ks = p & 3;
    const int lane = j & 63, rep = j >> 6;
    const int col = 16*t + (lane & 15);
    const float* w2c = W2 + 256*128 + col;
    for (int ii = 0; ii < 4; ii++) {
      const int i = rep*4 + ii;
      const int k = 32*ks + 8*(lane >> 4) + i;
      const float* w1r = W1 + (size_t)(128 + k)*256;
      float sa = 0.f, sb = 0.f;
      for (int m = 0; m < 256; m += 2) {
        sa = fmaf(w1r[m],   w2c[m*128],       sa);
        sb = fmaf(w1r[m+1], w2c[(m+1)*128],   sb);
      }
      wl2p[((t*4 + ks)*64 + lane)*8 + i] = f2bf(ln_g[k]*(sa + sb));
    }
  } else if (b == 1032) {
    // bf1p: u2 = b0@W1_1 + b1_1 ; s = u2@W2_1[:,col] + b2_1[col]
    float* u2 = sh;   // 256
    #pragma unroll
    for (int half = 0; half < 2; half++) {
      const int m = j + half*128;
      const float* w1c = W1 + 128*256 + m;
      float s = b1[256 + m];
      for (int k = 0; k < 128; k++) s = fmaf(ln_b[k], w1c[k*256], s);
      u2[m] = s;
    }
    __syncthreads();
    const int t = (j >> 2) & 7, g = j >> 5, r = j & 3;
    const int col = 16*t + 4*g + r;
    const float* w2c = W2 + 256*128 + col;
    float s = b2[128 + col];
    for (int m = 0; m < 256; m++) s = fmaf(u2[m], w2c[m*128], s);
    bf1p[j] = s;
  } else if (b == 1033) {
    // boutp: b1n@W_out + b_out (independent of WLf)
    const int t = (j >> 2) & 7, g = j >> 5, r = j & 3;
    const int col = 16*t + 4*g + r;
    float s = b_out[col];
    for (int k = 0; k < 128; k++) s = fmaf(ln_b[128 + k], W_out[k*128 + col], s);
    boutp[j] = s;
  } else if (b < 1066) {
    // woutp: diag(g1)@W_out transposed A-pack (independent of WLf)
    const int p = b - 1034, t = p >> 2, ks = p & 3;
    const int lane = j & 63, rep = j >> 6;
    const int col = 16*t + (lane & 15);
    for (int ii = 0; ii < 4; ii++) {
      const int i = rep*4 + ii;
      const int k = 32*ks + 8*(lane >> 4) + i;
      woutp[((t*4 + ks)*64 + lane)*8 + i] = f2bf(ln_g[128 + k] * W_out[k*128 + col]);
    }
  } else {
    // a1p block (t, q): k-range 8q..8q+7; 3-stage B -> U -> pack
    const int idx = b - 1066, t = idx >> 2, q = idx & 3;
    float* B = sh;          // [8][128]
    float* U = sh + 1024;   // [8][256]
    // stage A: B[kk][j]
    for (int kk = 0; kk < 8; kk++) {
      const int k = 8*q + kk;
      float s = 0.f;
      if (k < 20) {
        const float* wn = W_num + k*32;
        const float* wi = W_in + (size_t)(20 + k)*32*128 + j;
        for (int e = 0; e < 32; e++) s = fmaf(wn[e], wi[e*128], s);
      } else if (k == 20) {
        s = b_in[j];
        for (int f2 = 0; f2 < 20; f2++) {
          const float* bn = b_num + f2*32;
          const float* wi = W_in + (size_t)(20 + f2)*32*128 + j;
          for (int e = 0; e < 32; e++) s = fmaf(bn[e], wi[e*128], s);
        }
      }
      B[kk*128 + j] = s;
    }
    __syncthreads();
    // stage B: U[kk][m] = B[kk]@W1_0 (+ b1_0 for k==20)
    for (int kk = 0; kk < 8; kk++) {
      const int k = 8*q + kk;
      #pragma unroll
      for (int half = 0; half < 2; half++) {
        const int m = j + half*128;
        float s = 0.f;
        if (k <= 20) {
          const float* w1c = W1 + m;
          const float* Bk = B + kk*128;
          float sa = 0.f, sb = 0.f;
          for (int kx = 0; kx < 128; kx += 2) {
            sa = fmaf(Bk[kx],   w1c[kx*256],       sa);
            sb = fmaf(Bk[kx+1], w1c[(kx+1)*256],   sb);
          }
          s = sa + sb;
          if (k == 20) s += b1[m];
        }
        U[kk*256 + m] = s;
      }
    }
    __syncthreads();
    // stage C: one output per thread (16 lanes x 8 i for this (t,q))
    {
      const int lane16 = j & 15, i = j >> 4;
      const int lane = q*16 + lane16;
      const int k = 8*q + i;
      const int col = 32*(t >> 1) + 8*(lane16 >> 2) + 4*(t & 1) + (lane16 & 3);
      float v = 0.f;
      if (k <= 20) {
        const float* w2c = W2 + col;       // W2_0[m][col]
        const float* Uk = U + i*256;
        float sa = 0.f, sb = 0.f;
        for (int m = 0; m < 256; m += 2) {
          sa = fmaf(Uk[m],   w2c[m*128],       sa);
          sb = fmaf(Uk[m+1], w2c[(m+1)*128],   sb);
        }
        v = sa + sb;
        if (k == 20) v += b2[col];
      }
      a1p[(t*64 + lane)*8 + i] = f2bf(v);
    }
  }
}

// ---------------- mainK: fused gather + tail, 1024 thr, 1 block/CU ----------
// grid 768; block owns 128 rows. Gather: 16 waves x 8 rows. Tail: 8 waves x 16.
__global__ __launch_bounds__(1024, 1) void mainK(
    const float* __restrict__ x,
    const uint16_t* __restrict__ tcatp,
    const uint16_t* __restrict__ a1p,
    const uint16_t* __restrict__ wl2p,
    const uint16_t* __restrict__ woutp,
    const float* __restrict__ bf1p,
    const float* __restrict__ boutp,
    float* __restrict__ out)
{
  __shared__ __align__(16) unsigned char smem[162816];
  uint4* tbl4 = reinterpret_cast<uint4*>(smem);
  const char* tbl = reinterpret_cast<const char*>(smem);
  uint16_t* hst = reinterpret_cast<uint16_t*>(smem + 128000);   // 128 x 136 u16

  const int tid = threadIdx.x, lane = tid & 63, w = tid >> 6;   // w in 0..15
  const int r8 = lane >> 3, s = lane & 7;
  const int bid = blockIdx.x;

  // ---- pack this wave-row's 20 categorical codes (8 dup lanes share lines) ----
  const int myrow = w*8 + r8;
  uint32_t iw0, iw1, iw2, iw3, iw4;
  {
    const float* xr = x + ((size_t)bid*128 + myrow)*40;
    const f32x4 c0 = *reinterpret_cast<const f32x4*>(xr);
    const f32x4 c1 = *reinterpret_cast<const f32x4*>(xr + 4);
    const f32x4 c2 = *reinterpret_cast<const f32x4*>(xr + 8);
    const f32x4 c3 = *reinterpret_cast<const f32x4*>(xr + 12);
    const f32x4 c4 = *reinterpret_cast<const f32x4*>(xr + 16);
    iw0 = (uint32_t)c0[0] | ((uint32_t)c0[1]<<8) | ((uint32_t)c0[2]<<16) | ((uint32_t)c0[3]<<24);
    iw1 = (uint32_t)c1[0] | ((uint32_t)c1[1]<<8) | ((uint32_t)c1[2]<<16) | ((uint32_t)c1[3]<<24);
    iw2 = (uint32_t)c2[0] | ((uint32_t)c2[1]<<8) | ((uint32_t)c2[2]<<16) | ((uint32_t)c2[3]<<24);
    iw3 = (uint32_t)c3[0] | ((uint32_t)c3[1]<<8) | ((uint32_t)c3[2]<<16) | ((uint32_t)c3[3]<<24);
    iw4 = (uint32_t)c4[0] | ((uint32_t)c4[1]<<8) | ((uint32_t)c4[2]<<16) | ((uint32_t)c4[3]<<24);
  }

  // ====== phases A/B: LDS gather of each column half ======
  for (int h = 0; h < 2; h++) {
    {  // stage half via direct global->LDS (no DS-pipe instr issue)
      const uint4* src = reinterpret_cast<const uint4*>(tcatp) + h*8000;
      for (int i = tid; i < 8000; i += 1024)
        GLDS16(src + i, tbl4 + i);
    }
    __syncthreads();

    const uint32_t iw[5] = {iw0, iw1, iw2, iw3, iw4};
    uint4 b[20];
    #pragma unroll
    for (int f = 0; f < 20; f++) {
      const int idx = (int)((iw[f >> 2] >> (8*(f & 3))) & 0xffu);
      b[f] = *reinterpret_cast<const uint4*>(tbl + (f*50 + idx)*128 + s*16);
    }
    f32x4 a0 = {0.f,0.f,0.f,0.f}, a1v = {0.f,0.f,0.f,0.f};
    #pragma unroll
    for (int f = 0; f < 20; f++) {
      a0[0] += bflo(b[f].x); a0[1] += bfhi(b[f].x);
      a0[2] += bflo(b[f].y); a0[3] += bfhi(b[f].y);
      a1v[0] += bflo(b[f].z); a1v[1] += bfhi(b[f].z);
      a1v[2] += bflo(b[f].w); a1v[3] += bfhi(b[f].w);
    }
    const uint4 o = { pkbf(a0[0], a0[1]), pkbf(a0[2], a0[3]),
                      pkbf(a1v[0], a1v[1]), pkbf(a1v[2], a1v[3]) };
    *reinterpret_cast<uint4*>(hst + myrow*136 + 64*h + 8*s) = o;
    __syncthreads();
  }

  // ====== phase C: stage weights into dead table region ======
  uint16_t* wl2l = reinterpret_cast<uint16_t*>(smem);            // 32768 B
  uint16_t* wol  = reinterpret_cast<uint16_t*>(smem + 32768);    // 32768 B
  uint16_t* a1l  = reinterpret_cast<uint16_t*>(smem + 65536);    //  8192 B
  float*    bf1l = reinterpret_cast<float*>(smem + 73728);       //   512 B
  float*    boll = reinterpret_cast<float*>(smem + 74240);       //   512 B
  {
    for (int i = tid; i < 2048; i += 1024)
      GLDS16(reinterpret_cast<const uint4*>(wl2p) + i, reinterpret_cast<uint4*>(wl2l) + i);
    for (int i = tid; i < 2048; i += 1024)
      GLDS16(reinterpret_cast<const uint4*>(woutp) + i, reinterpret_cast<uint4*>(wol) + i);
    if (tid < 512)
      GLDS16(reinterpret_cast<const uint4*>(a1p) + tid, reinterpret_cast<uint4*>(a1l) + tid);
    else if (tid < 544)
      GLDS16(reinterpret_cast<const uint4*>(bf1p) + (tid - 512), reinterpret_cast<uint4*>(bf1l) + (tid - 512));
    else if (tid < 576)
      GLDS16(reinterpret_cast<const uint4*>(boutp) + (tid - 544), reinterpret_cast<uint4*>(boll) + (tid - 544));
  }
  __syncthreads();

  // ====== tail: waves 0..7, 16 rows each (r9-r11 verified body) ======
  if (w < 8) {
    uint16_t* hb = reinterpret_cast<uint16_t*>(smem + 74752) + w*2176;  // 16x136 u16
    const int g = lane >> 4, c16 = lane & 15;
    const int row = w*16 + c16;
    const size_t grow = (size_t)bid*128 + row;

    // numeric bf16 fragment from x (lane-local; rows k>20 hit zero a1p rows)
    short8 xf;
    {
      uint32_t* xw = (uint32_t*)&xf;
      const float* xn = x + grow*40 + 20;
      if (g < 2) {
        const f32x4 a = *reinterpret_cast<const f32x4*>(xn + 8*g);
        const f32x4 b = *reinterpret_cast<const f32x4*>(xn + 8*g + 4);
        xw[0] = pkbf(a[0], a[1]); xw[1] = pkbf(a[2], a[3]);
        xw[2] = pkbf(b[0], b[1]); xw[3] = pkbf(b[2], b[3]);
      } else if (g == 2) {
        const f32x4 a = *reinterpret_cast<const f32x4*>(xn + 16);
        xw[0] = pkbf(a[0], a[1]); xw[1] = pkbf(a[2], a[3]);
        xw[2] = pkbf(1.0f, 0.0f); xw[3] = 0;
      } else {
        xw[0] = 0; xw[1] = 0; xw[2] = 0; xw[3] = 0;
      }
    }

    // numeric fold: acc[t=2ks+hl][r] = cols 32ks+8g+4hl+r
    f32x4 acc[8];
    #pragma unroll
    for (int t = 0; t < 8; t++) {
      const short8 af = *reinterpret_cast<const short8*>(a1l + (t*64 + lane)*8);
      acc[t] = __builtin_amdgcn_mfma_f32_16x16x32_bf16(af, xf, (f32x4){0.f,0.f,0.f,0.f}, 0, 0, 0);
    }

    // add gathered categorical part from hstate (slot-major bf16)
    const uint16_t* h1row = hst + row*136;
    #pragma unroll
    for (int ks = 0; ks < 4; ks++)
      #pragma unroll
      for (int hl = 0; hl < 2; hl++) {
        const int inner = 8*g + 4*hl;
        const int tc = 2*ks + (inner >> 4);
        const int gc = (inner & 15) >> 2;
        const int jj = tc & 3;
        const int P = 64*(tc >> 2) + 8*(2*gc + (jj >> 1)) + 4*(jj & 1);
        const uint2 u = *reinterpret_cast<const uint2*>(h1row + P);
        const int t = 2*ks + hl;
        acc[t][0] += bflo(u.x); acc[t][1] += bfhi(u.x);
        acc[t][2] += bflo(u.y); acc[t][3] += bfhi(u.y);
      }

    // LN0 (gamma/beta folded downstream)
    float sA = 0.f, qA = 0.f;
    #pragma unroll
    for (int t = 0; t < 8; t++)
      #pragma unroll
      for (int r = 0; r < 4; r++) { const float v = acc[t][r]; sA += v; qA = fmaf(v, v, qA); }
    sA += __shfl_xor(sA, 16); sA += __shfl_xor(sA, 32);
    qA += __shfl_xor(qA, 16); qA += __shfl_xor(qA, 32);
    const float mu = sA * (1.f/128.f);
    const float rs = rsqrtf(qA*(1.f/128.f) - mu*mu + LN_EPS);

    short8 a2[4];
    #pragma unroll
    for (int ks = 0; ks < 4; ks++) {
      uint32_t* aw = (uint32_t*)&a2[ks];
      aw[0] = pkbf((acc[2*ks][0]-mu)*rs,   (acc[2*ks][1]-mu)*rs);
      aw[1] = pkbf((acc[2*ks][2]-mu)*rs,   (acc[2*ks][3]-mu)*rs);
      aw[2] = pkbf((acc[2*ks+1][0]-mu)*rs, (acc[2*ks+1][1]-mu)*rs);
      aw[3] = pkbf((acc[2*ks+1][2]-mu)*rs, (acc[2*ks+1][3]-mu)*rs);
    }

    // GEMM2': acc2 = z1 @ WL1' (+bf1')
    f32x4 acc2[8];
    #pragma unroll
    for (int t = 0; t < 8; t++) {
      acc2[t] = *reinterpret_cast<const f32x4*>(bf1l + g*32 + t*4);
      #pragma unroll
      for (int ks = 0; ks < 4; ks++) {
        const short8 wf = *reinterpret_cast<const short8*>(wl2l + ((t*4 + ks)*64 + lane)*8);
        acc2[t] = __builtin_amdgcn_mfma_f32_16x16x32_bf16(wf, a2[ks], acc2[t], 0, 0, 0);
      }
    }

    // LN1
    float s2 = 0.f, q2 = 0.f;
    #pragma unroll
    for (int t = 0; t < 8; t++)
      #pragma unroll
      for (int r = 0; r < 4; r++) { const float v = acc2[t][r]; s2 += v; q2 = fmaf(v, v, q2); }
    s2 += __shfl_xor(s2, 16); s2 += __shfl_xor(s2, 32);
    q2 += __shfl_xor(q2, 16); q2 += __shfl_xor(q2, 32);
    const float mu2 = s2 * (1.f/128.f);
    const float rs2 = rsqrtf(q2*(1.f/128.f) - mu2*mu2 + LN_EPS);

    #pragma unroll
    for (int t = 0; t < 8; t++) {
      const uint32x2 v = { pkbf((acc2[t][0]-mu2)*rs2, (acc2[t][1]-mu2)*rs2),
                           pkbf((acc2[t][2]-mu2)*rs2, (acc2[t][3]-mu2)*rs2) };
      *reinterpret_cast<uint32x2*>(hb + c16*136 + 16*t + 4*g) = v;
    }
    asm volatile("s_waitcnt lgkmcnt(0)" ::: "memory");

    // GEMM3': out = z2 @ Wout' + bout'
    short8 a3[4];
    #pragma unroll
    for (int ks = 0; ks < 4; ks++)
      a3[ks] = *reinterpret_cast<const short8*>(hb + c16*136 + 32*ks + 8*g);
    float* orow = out + grow*128;
    #pragma unroll
    for (int t = 0; t < 8; t++) {
      f32x4 a3c = *reinterpret_cast<const f32x4*>(boll + g*32 + t*4);
      #pragma unroll
      for (int ks = 0; ks < 4; ks++) {
        const short8 wf = *reinterpret_cast<const short8*>(wol + ((t*4 + ks)*64 + lane)*8);
        a3c = __builtin_amdgcn_mfma_f32_16x16x32_bf16(wf, a3[ks], a3c, 0, 0, 0);
      }
      __builtin_nontemporal_store(a3c, reinterpret_cast<f32x4*>(orow + 16*t + 4*g));
    }
  }
}

// ---------------- launcher ----------------
extern "C" void kernel_launch(void* const* d_in, const int* in_sizes, int n_in,
                              void* d_out, int out_size, void* d_ws, size_t ws_size,
                              hipStream_t stream)
{
  const float* x     = (const float*)d_in[0];
  const float* emb   = (const float*)d_in[1];
  const float* W_num = (const float*)d_in[2];
  const float* b_num = (const float*)d_in[3];
  const float* W_in  = (const float*)d_in[4];
  const float* b_in  = (const float*)d_in[5];
  const float* W1    = (const float*)d_in[6];
  const float* b1    = (const float*)d_in[7];
  const float* W2    = (const float*)d_in[8];
  const float* b2    = (const float*)d_in[9];
  const float* ln_g  = (const float*)d_in[10];
  const float* ln_b  = (const float*)d_in[11];
  const float* W_out = (const float*)d_in[12];
  const float* b_out = (const float*)d_in[13];
  float* out = (float*)d_out;

  char* ws = (char*)d_ws;
  uint16_t* tcatp = (uint16_t*)(ws + 0);       // 256000 B
  uint16_t* wl2p  = (uint16_t*)(ws + 256000);  //  32768 B
  uint16_t* woutp = (uint16_t*)(ws + 288768);  //  32768 B
  uint16_t* a1p   = (uint16_t*)(ws + 321536);  //   8192 B
  float*    bf1p  = (float*)(ws + 329728);     //    512 B
  float*    boutp = (float*)(ws + 330240);     //    512 B

  prep<<<dim3(1098), dim3(128), 0, stream>>>(emb, W_num, b_num, W_in, b_in,
                                             W1, b1, W2, b2, ln_g, ln_b,
                                             W_out, b_out,
                                             tcatp, wl2p, bf1p, a1p, woutp, boutp);
  mainK<<<dim3(768), dim3(1024), 0, stream>>>(x, tcatp, a1p, wl2p, woutp,
                                              bf1p, boutp, out);
}

// Round 13
// 71.841 us; speedup vs baseline: 1.0434x; 1.0434x over previous
//
#include <hip/hip_runtime.h>
#include <hip/hip_bf16.h>
#include <stdint.h>
#include <stddef.h>

// ---------------------------------------------------------------------------
// FixedEmbedderNN — round 13:
//  - pre1/pre2 reverted to r11 (WLf computed once; measured faster than the
//    merged prep of r12).
//  - mainK: quarter-granular double-buffered staging pipeline. Each barrier
//    interval: issue GLDS for next quarter (other buffer) -> gather current
//    quarter (ds_read_b64, lane = (row, slot4, d)) -> __syncthreads (implicit
//    vmcnt(0) drains the issued staging exactly when next interval needs it).
//    Weight staging (74,752 B contiguous in ws) issued into dead buffers
//    after Q2/Q3 gathers. hstate layout and tail are byte-identical to the
//    verified r11/r12 versions.
//  LDS: bufs [0,64000)+[64000,128000), hstate [128000,162816);
//  phase C: weights [0,74752), hbuf [74752,109568).
// ---------------------------------------------------------------------------

typedef __attribute__((ext_vector_type(8))) short short8;
typedef __attribute__((ext_vector_type(4))) float f32x4;
typedef __attribute__((ext_vector_type(2))) uint32_t uint32x2;

#define LN_EPS 1e-5f

#define GLDS16(g, l) __builtin_amdgcn_global_load_lds( \
    (const __attribute__((address_space(1))) uint32_t*)(g), \
    (__attribute__((address_space(3))) uint32_t*)(l), 16, 0, 0)

__device__ __forceinline__ float bflo(uint32_t u){ union{uint32_t u;float f;} c; c.u = u<<16; return c.f; }
__device__ __forceinline__ float bfhi(uint32_t u){ union{uint32_t u;float f;} c; c.u = u&0xffff0000u; return c.f; }
__device__ __forceinline__ uint16_t f2bf(float f){
  union{ __hip_bfloat16 h; uint16_t u; } c; c.h = __float2bfloat16(f); return c.u;
}
__device__ __forceinline__ uint32_t pkbf(float lo, float hi){
  return (uint32_t)f2bf(lo) | ((uint32_t)f2bf(hi)<<16);
}

// ---------------- precompute kernel 1 (no deps) — r11 verbatim ----------------
__global__ __launch_bounds__(128) void pre1(
    const float* __restrict__ W_num, const float* __restrict__ b_num,
    const float* __restrict__ W_in,  const float* __restrict__ b_in,
    const float* __restrict__ W1,    const float* __restrict__ b1,
    const float* __restrict__ W2,    const float* __restrict__ b2,
    const float* __restrict__ W_out, const float* __restrict__ b_out,
    const float* __restrict__ ln_g,  const float* __restrict__ ln_b,
    float* __restrict__ WLf,    // [2][128][128]
    float* __restrict__ Bnum,   // [21][128]
    float* __restrict__ bfold,  // [2][128]
    uint16_t* __restrict__ woutp, // Wout' transposed pack
    float* __restrict__ boutp)    // bout' permuted [g*32+t*4+r]
{
  const int b = blockIdx.x, j = threadIdx.x;
  if (b < 256) {                       // WL = W1@W2 per layer (4-way ILP)
    const int l = b >> 7, k = b & 127;
    const float* w1r = W1 + (l*128 + k)*256;
    const float* w2  = W2 + l*256*128;
    float sa = 0.f, sb = 0.f, sc = 0.f, sd = 0.f;
    for (int m = 0; m < 256; m += 4) {
      sa = fmaf(w1r[m],   w2[m*128 + j],       sa);
      sb = fmaf(w1r[m+1], w2[(m+1)*128 + j],   sb);
      sc = fmaf(w1r[m+2], w2[(m+2)*128 + j],   sc);
      sd = fmaf(w1r[m+3], w2[(m+3)*128 + j],   sd);
    }
    WLf[(l*128 + k)*128 + j] = (sa + sb) + (sc + sd);
  } else if (b < 277) {                // Bnum rows
    const int r = b - 256;
    if (r < 20) {
      const float* wn = W_num + r*32;
      const float* wi = W_in + (size_t)(20 + r)*32*128;
      float s = 0.f;
      for (int e = 0; e < 32; e++) s = fmaf(wn[e], wi[e*128 + j], s);
      Bnum[r*128 + j] = s;
    } else {
      float s = b_in[j];
      for (int f = 0; f < 20; f++) {
        const float* bn = b_num + f*32;
        const float* wi = W_in + (size_t)(20 + f)*32*128;
        for (int e = 0; e < 32; e++) s = fmaf(bn[e], wi[e*128 + j], s);
      }
      Bnum[20*128 + j] = s;
    }
  } else if (b < 279) {                // bfold = b1@W2 + b2
    const int l = b - 277;
    const float* b1r = b1 + l*256;
    const float* w2  = W2 + l*256*128;
    float s = b2[l*128 + j];
    for (int k = 0; k < 256; k++) s = fmaf(b1r[k], w2[k*128 + j], s);
    bfold[l*128 + j] = s;
  } else if (b < 311) {                // woutp: Wout' = diag(g1)@W_out, transposed A-pack
    const int p = b - 279, t = p >> 2, ks = p & 3;
    const int lane = j & 63, rep = j >> 6;
    const int col = 16*t + (lane & 15);
    for (int ii = 0; ii < 4; ii++) {
      const int i = rep*4 + ii;
      const int k = 32*ks + 8*(lane >> 4) + i;
      woutp[((t*4 + ks)*64 + lane)*8 + i] = f2bf(ln_g[128 + k] * W_out[k*128 + col]);
    }
  } else {                             // boutp (permuted): b1n@W_out + b_out
    const int t = (j >> 2) & 7, g = j >> 5, r = j & 3;
    const int col = 16*t + 4*g + r;
    float s = b_out[col];
    for (int k = 0; k < 128; k++) s = fmaf(ln_b[128 + k], W_out[k*128 + col], s);
    boutp[j] = s;
  }
}

// ---------------- precompute kernel 2 (depends on pre1) — r11 verbatim --------
__global__ __launch_bounds__(128) void pre2(
    const float* __restrict__ emb, const float* __restrict__ W_in,
    const float* __restrict__ ln_g, const float* __restrict__ ln_b,
    const float* __restrict__ WLf, const float* __restrict__ Bnum,
    const float* __restrict__ bfold,
    uint16_t* __restrict__ tcatp, // [2][20][50][64] bf16 slot-major
    uint16_t* __restrict__ wl2p,  // WL1' transposed pack
    float* __restrict__ bf1p,     // bf1' permuted
    uint16_t* __restrict__ a1p)   // A1^T pack, 8-run col map
{
  const int b = blockIdx.x, j = threadIdx.x;
  __shared__ float sh[128];
  if (b < 1000) {                      // Tcat1 = emb@W_in_slice@WL_0, slot-major store
    const int f = b / 50, c = b % 50;
    const float* e  = emb + (f*50 + c)*32;
    const float* wi = W_in + (size_t)f*32*128;
    float s = 0.f;
    for (int k = 0; k < 32; k++) s = fmaf(e[k], wi[k*128 + j], s);
    sh[j] = s;
    __syncthreads();
    float sa = 0.f, sb = 0.f, sc = 0.f, sd = 0.f;    // 4-way ILP
    for (int k = 0; k < 128; k += 4) {
      sa = fmaf(sh[k],   WLf[k*128 + j],       sa);
      sb = fmaf(sh[k+1], WLf[(k+1)*128 + j],   sb);
      sc = fmaf(sh[k+2], WLf[(k+2)*128 + j],   sc);
      sd = fmaf(sh[k+3], WLf[(k+3)*128 + j],   sd);
    }
    const float s2 = (sa + sb) + (sc + sd);
    const int t = j >> 4, g = (j >> 2) & 3, r = j & 3;
    const int h = t >> 2, jj = t & 3;
    const int slot = 2*g + (jj >> 1);
    tcatp[((h*20 + f)*50 + c)*64 + slot*8 + (jj & 1)*4 + r] = f2bf(s2);
  } else if (b < 1032) {               // wl2p: WL1' = diag(g0)@WL_1, transposed A-pack
    const int p = b - 1000, t = p >> 2, ks = p & 3;
    const int lane = j & 63, rep = j >> 6;
    const int col = 16*t + (lane & 15);
    const float* wl1 = WLf + 16384;
    for (int ii = 0; ii < 4; ii++) {
      const int i = rep*4 + ii;
      const int k = 32*ks + 8*(lane >> 4) + i;
      wl2p[((t*4 + ks)*64 + lane)*8 + i] = f2bf(ln_g[k] * wl1[k*128 + col]);
    }
  } else if (b == 1032) {              // bf1p (permuted): b0@WL_1 + bfold_1
    const int t = (j >> 2) & 7, g = j >> 5, r = j & 3;
    const int col = 16*t + 4*g + r;
    const float* wl1 = WLf + 16384;
    float s = bfold[128 + col];
    for (int k = 0; k < 128; k++) s = fmaf(ln_b[k], wl1[k*128 + col], s);
    bf1p[j] = s;
  } else {                             // a1p with 8-run col map (4-way ILP)
    const int t = b - 1033;
    const int lane = j & 63, rep = j >> 6;
    const int p = lane & 15;
    const int col = 32*(t >> 1) + 8*(p >> 2) + 4*(t & 1) + (p & 3);
    for (int ii = 0; ii < 4; ii++) {
      const int i = rep*4 + ii;
      const int k = 8*(lane >> 4) + i;
      float v = 0.f;
      if (k <= 20) {
        if (k == 20) v = bfold[col];
        float va = 0.f, vb = 0.f, vc = 0.f, vd = 0.f;
        for (int m = 0; m < 128; m += 4) {
          va = fmaf(Bnum[k*128 + m],   WLf[m*128 + col],       va);
          vb = fmaf(Bnum[k*128 + m+1], WLf[(m+1)*128 + col],   vb);
          vc = fmaf(Bnum[k*128 + m+2], WLf[(m+2)*128 + col],   vc);
          vd = fmaf(Bnum[k*128 + m+3], WLf[(m+3)*128 + col],   vd);
        }
        v += (va + vb) + (vc + vd);
      }
      a1p[(t*64 + lane)*8 + i] = f2bf(v);
    }
  }
}

// ---------------- mainK: quarter-pipelined gather + tail, 1024 thr ----------
// grid 768; block owns 128 rows. Gather: 16 waves x 8 rows. Tail: 8 waves x 16.
__global__ __launch_bounds__(1024, 1) void mainK(
    const float* __restrict__ x,
    const uint16_t* __restrict__ tcatp,
    const uint4* __restrict__ wsrc,     // wl2p|woutp|a1p|bf1p|boutp (74752 B)
    float* __restrict__ out)
{
  __shared__ __align__(16) unsigned char smem[162816];
  uint16_t* hst = reinterpret_cast<uint16_t*>(smem + 128000);   // 128 x 136 u16

  const int tid = threadIdx.x, lane = tid & 63, w = tid >> 6;   // w in 0..15
  const int r8 = (lane >> 3) & 7;        // row within wave
  const int s4 = (lane >> 1) & 3;        // 16B slot within quarter
  const int d  = lane & 1;               // low/high 8B of the slot
  const int bid = blockIdx.x;
  const char* tcb = (const char*)tcatp;

  // ---- pack this wave-row's 20 categorical codes ----
  const int myrow = w*8 + r8;
  uint32_t iw0, iw1, iw2, iw3, iw4;
  {
    const float* xr = x + ((size_t)bid*128 + myrow)*40;
    const f32x4 c0 = *reinterpret_cast<const f32x4*>(xr);
    const f32x4 c1 = *reinterpret_cast<const f32x4*>(xr + 4);
    const f32x4 c2 = *reinterpret_cast<const f32x4*>(xr + 8);
    const f32x4 c3 = *reinterpret_cast<const f32x4*>(xr + 12);
    const f32x4 c4 = *reinterpret_cast<const f32x4*>(xr + 16);
    iw0 = (uint32_t)c0[0] | ((uint32_t)c0[1]<<8) | ((uint32_t)c0[2]<<16) | ((uint32_t)c0[3]<<24);
    iw1 = (uint32_t)c1[0] | ((uint32_t)c1[1]<<8) | ((uint32_t)c1[2]<<16) | ((uint32_t)c1[3]<<24);
    iw2 = (uint32_t)c2[0] | ((uint32_t)c2[1]<<8) | ((uint32_t)c2[2]<<16) | ((uint32_t)c2[3]<<24);
    iw3 = (uint32_t)c3[0] | ((uint32_t)c3[1]<<8) | ((uint32_t)c3[2]<<16) | ((uint32_t)c3[3]<<24);
    iw4 = (uint32_t)c4[0] | ((uint32_t)c4[1]<<8) | ((uint32_t)c4[2]<<16) | ((uint32_t)c4[3]<<24);
  }

  // quarter q = (half h=q>>1, slot-group sg=q&1): 64B sub-block of each 128B row
  auto stageQ = [&](int q, int b) {
    char* dst = (char*)smem + b*64000;
    const char* srcb = tcb + (q >> 1)*128000 + (q & 1)*64;
    for (int u = tid; u < 4000; u += 1024)
      GLDS16(srcb + (u >> 2)*128 + (u & 3)*16, dst + u*16);
  };
  auto stageW = [&](int lo, int hi) {
    for (int u = tid + lo; u < hi; u += 1024)
      GLDS16(wsrc + u, reinterpret_cast<uint4*>(smem) + u);
  };
  auto gatherQ = [&](int q, int b) {
    const char* buf = (const char*)smem + b*64000;
    const uint32_t iw[5] = {iw0, iw1, iw2, iw3, iw4};
    uint2 bb[20];
    #pragma unroll
    for (int f = 0; f < 20; f++) {
      const int idx = (int)((iw[f >> 2] >> (8*(f & 3))) & 0xffu);
      bb[f] = *reinterpret_cast<const uint2*>(buf + (f*50 + idx)*64 + s4*16 + d*8);
    }
    float a0 = 0.f, a1 = 0.f, a2 = 0.f, a3 = 0.f;
    #pragma unroll
    for (int f = 0; f < 20; f++) {
      a0 += bflo(bb[f].x); a1 += bfhi(bb[f].x);
      a2 += bflo(bb[f].y); a3 += bfhi(bb[f].y);
    }
    const uint2 o = { pkbf(a0, a1), pkbf(a2, a3) };
    *reinterpret_cast<uint2*>(hst + myrow*136 + (q >> 1)*64 + ((q & 1)*4 + s4)*8 + d*4) = o;
  };

  // ====== pipelined staging + gather (barriers drain issued GLDS) ======
  stageQ(0, 0);                     __syncthreads();
  stageQ(1, 1);  gatherQ(0, 0);     __syncthreads();
  stageQ(2, 0);  gatherQ(1, 1);     __syncthreads();
  stageQ(3, 1);  gatherQ(2, 0);     __syncthreads();
  stageW(0, 4000); gatherQ(3, 1);   __syncthreads();   // weights into dead buf0
  stageW(4000, 4672);               __syncthreads();   // rest into dead buf1

  // ====== tail: waves 0..7, 16 rows each (r9-r12 verified body) ======
  uint16_t* wl2l = reinterpret_cast<uint16_t*>(smem);            // 32768 B
  uint16_t* wol  = reinterpret_cast<uint16_t*>(smem + 32768);    // 32768 B
  uint16_t* a1l  = reinterpret_cast<uint16_t*>(smem + 65536);    //  8192 B
  float*    bf1l = reinterpret_cast<float*>(smem + 73728);       //   512 B
  float*    boll = reinterpret_cast<float*>(smem + 74240);       //   512 B

  if (w < 8) {
    uint16_t* hb = reinterpret_cast<uint16_t*>(smem + 74752) + w*2176;  // 16x136 u16
    const int g = lane >> 4, c16 = lane & 15;
    const int row = w*16 + c16;
    const size_t grow = (size_t)bid*128 + row;

    // numeric bf16 fragment from x (lane-local; rows k>20 hit zero a1p rows)
    short8 xf;
    {
      uint32_t* xw = (uint32_t*)&xf;
      const float* xn = x + grow*40 + 20;
      if (g < 2) {
        const f32x4 a = *reinterpret_cast<const f32x4*>(xn + 8*g);
        const f32x4 b = *reinterpret_cast<const f32x4*>(xn + 8*g + 4);
        xw[0] = pkbf(a[0], a[1]); xw[1] = pkbf(a[2], a[3]);
        xw[2] = pkbf(b[0], b[1]); xw[3] = pkbf(b[2], b[3]);
      } else if (g == 2) {
        const f32x4 a = *reinterpret_cast<const f32x4*>(xn + 16);
        xw[0] = pkbf(a[0], a[1]); xw[1] = pkbf(a[2], a[3]);
        xw[2] = pkbf(1.0f, 0.0f); xw[3] = 0;
      } else {
        xw[0] = 0; xw[1] = 0; xw[2] = 0; xw[3] = 0;
      }
    }

    // numeric fold: acc[t=2ks+hl][r] = cols 32ks+8g+4hl+r
    f32x4 acc[8];
    #pragma unroll
    for (int t = 0; t < 8; t++) {
      const short8 af = *reinterpret_cast<const short8*>(a1l + (t*64 + lane)*8);
      acc[t] = __builtin_amdgcn_mfma_f32_16x16x32_bf16(af, xf, (f32x4){0.f,0.f,0.f,0.f}, 0, 0, 0);
    }

    // add gathered categorical part from hstate (slot-major bf16)
    const uint16_t* h1row = hst + row*136;
    #pragma unroll
    for (int ks = 0; ks < 4; ks++)
      #pragma unroll
      for (int hl = 0; hl < 2; hl++) {
        const int inner = 8*g + 4*hl;
        const int tc = 2*ks + (inner >> 4);
        const int gc = (inner & 15) >> 2;
        const int jj = tc & 3;
        const int P = 64*(tc >> 2) + 8*(2*gc + (jj >> 1)) + 4*(jj & 1);
        const uint2 u = *reinterpret_cast<const uint2*>(h1row + P);
        const int t = 2*ks + hl;
        acc[t][0] += bflo(u.x); acc[t][1] += bfhi(u.x);
        acc[t][2] += bflo(u.y); acc[t][3] += bfhi(u.y);
      }

    // LN0 (gamma/beta folded downstream)
    float sA = 0.f, qA = 0.f;
    #pragma unroll
    for (int t = 0; t < 8; t++)
      #pragma unroll
      for (int r = 0; r < 4; r++) { const float v = acc[t][r]; sA += v; qA = fmaf(v, v, qA); }
    sA += __shfl_xor(sA, 16); sA += __shfl_xor(sA, 32);
    qA += __shfl_xor(qA, 16); qA += __shfl_xor(qA, 32);
    const float mu = sA * (1.f/128.f);
    const float rs = rsqrtf(qA*(1.f/128.f) - mu*mu + LN_EPS);

    short8 a2[4];
    #pragma unroll
    for (int ks = 0; ks < 4; ks++) {
      uint32_t* aw = (uint32_t*)&a2[ks];
      aw[0] = pkbf((acc[2*ks][0]-mu)*rs,   (acc[2*ks][1]-mu)*rs);
      aw[1] = pkbf((acc[2*ks][2]-mu)*rs,   (acc[2*ks][3]-mu)*rs);
      aw[2] = pkbf((acc[2*ks+1][0]-mu)*rs, (acc[2*ks+1][1]-mu)*rs);
      aw[3] = pkbf((acc[2*ks+1][2]-mu)*rs, (acc[2*ks+1][3]-mu)*rs);
    }

    // GEMM2': acc2 = z1 @ WL1' (+bf1')
    f32x4 acc2[8];
    #pragma unroll
    for (int t = 0; t < 8; t++) {
      acc2[t] = *reinterpret_cast<const f32x4*>(bf1l + g*32 + t*4);
      #pragma unroll
      for (int ks = 0; ks < 4; ks++) {
        const short8 wf = *reinterpret_cast<const short8*>(wl2l + ((t*4 + ks)*64 + lane)*8);
        acc2[t] = __builtin_amdgcn_mfma_f32_16x16x32_bf16(wf, a2[ks], acc2[t], 0, 0, 0);
      }
    }

    // LN1
    float s2 = 0.f, q2 = 0.f;
    #pragma unroll
    for (int t = 0; t < 8; t++)
      #pragma unroll
      for (int r = 0; r < 4; r++) { const float v = acc2[t][r]; s2 += v; q2 = fmaf(v, v, q2); }
    s2 += __shfl_xor(s2, 16); s2 += __shfl_xor(s2, 32);
    q2 += __shfl_xor(q2, 16); q2 += __shfl_xor(q2, 32);
    const float mu2 = s2 * (1.f/128.f);
    const float rs2 = rsqrtf(q2*(1.f/128.f) - mu2*mu2 + LN_EPS);

    #pragma unroll
    for (int t = 0; t < 8; t++) {
      const uint32x2 v = { pkbf((acc2[t][0]-mu2)*rs2, (acc2[t][1]-mu2)*rs2),
                           pkbf((acc2[t][2]-mu2)*rs2, (acc2[t][3]-mu2)*rs2) };
      *reinterpret_cast<uint32x2*>(hb + c16*136 + 16*t + 4*g) = v;
    }
    asm volatile("s_waitcnt lgkmcnt(0)" ::: "memory");

    // GEMM3': out = z2 @ Wout' + bout'
    short8 a3[4];
    #pragma unroll
    for (int ks = 0; ks < 4; ks++)
      a3[ks] = *reinterpret_cast<const short8*>(hb + c16*136 + 32*ks + 8*g);
    float* orow = out + grow*128;
    #pragma unroll
    for (int t = 0; t < 8; t++) {
      f32x4 a3c = *reinterpret_cast<const f32x4*>(boll + g*32 + t*4);
      #pragma unroll
      for (int ks = 0; ks < 4; ks++) {
        const short8 wf = *reinterpret_cast<const short8*>(wol + ((t*4 + ks)*64 + lane)*8);
        a3c = __builtin_amdgcn_mfma_f32_16x16x32_bf16(wf, a3[ks], a3c, 0, 0, 0);
      }
      __builtin_nontemporal_store(a3c, reinterpret_cast<f32x4*>(orow + 16*t + 4*g));
    }
  }
}

// ---------------- launcher ----------------
extern "C" void kernel_launch(void* const* d_in, const int* in_sizes, int n_in,
                              void* d_out, int out_size, void* d_ws, size_t ws_size,
                              hipStream_t stream)
{
  const float* x     = (const float*)d_in[0];
  const float* emb   = (const float*)d_in[1];
  const float* W_num = (const float*)d_in[2];
  const float* b_num = (const float*)d_in[3];
  const float* W_in  = (const float*)d_in[4];
  const float* b_in  = (const float*)d_in[5];
  const float* W1    = (const float*)d_in[6];
  const float* b1    = (const float*)d_in[7];
  const float* W2    = (const float*)d_in[8];
  const float* b2    = (const float*)d_in[9];
  const float* ln_g  = (const float*)d_in[10];
  const float* ln_b  = (const float*)d_in[11];
  const float* W_out = (const float*)d_in[12];
  const float* b_out = (const float*)d_in[13];
  float* out = (float*)d_out;

  char* ws = (char*)d_ws;
  float*    WLf   = (float*)(ws + 0);          // 131072 B
  float*    Bnum  = (float*)(ws + 131072);     //  10752 B
  float*    bfold = (float*)(ws + 141824);     //   1024 B
  uint16_t* tcatp = (uint16_t*)(ws + 142848);  // 256000 B
  uint16_t* wl2p  = (uint16_t*)(ws + 398848);  //  32768 B  ┐ contiguous
  uint16_t* woutp = (uint16_t*)(ws + 431616);  //  32768 B  │ 74752 B
  uint16_t* a1p   = (uint16_t*)(ws + 464384);  //   8192 B  │ weight
  float*    bf1p  = (float*)(ws + 472576);     //    512 B  │ block
  float*    boutp = (float*)(ws + 473088);     //    512 B  ┘

  pre1<<<dim3(312), dim3(128), 0, stream>>>(W_num, b_num, W_in, b_in, W1, b1, W2, b2,
                                            W_out, b_out, ln_g, ln_b,
                                            WLf, Bnum, bfold, woutp, boutp);
  pre2<<<dim3(1041), dim3(128), 0, stream>>>(emb, W_in, ln_g, ln_b, WLf, Bnum, bfold,
                                             tcatp, wl2p, bf1p, a1p);
  mainK<<<dim3(768), dim3(1024), 0, stream>>>(x, tcatp,
                                              (const uint4*)(ws + 398848), out);
}